// Round 1
// baseline (227.626 us; speedup 1.0000x reference)
//
#include <hip/hip_runtime.h>

// Problem constants: B=512, T=4096, C=7, H=3 ; N = 2,097,152 rows
constexpr long long N_ROWS = 512LL * 4096LL;
constexpr int BLOCK = 256;                 // 4 waves
constexpr int RPT   = 4;                   // rows per thread (keeps all loads 16B-aligned)
constexpr int NBLOCKS = (int)(N_ROWS / ((long long)BLOCK * RPT));  // 2048

// Direct-to-register streaming kernel. No LDS staging: each row is consumed by
// exactly one thread (no cross-thread reuse), so LDS only ever served as a
// coalescing trampoline — at the cost of 57.9KB/block (2 blocks/CU, 17% occ)
// and a vmcnt(0)+barrier drain per 28KB chunk. With 4 consecutive rows per
// thread every input becomes a 16B-aligned dwordx4:
//   out_h : 4 rows * 7 = 28 floats = 7 x float4   (byte off 112*g, 16B-aligned)
//   labels: 4 rows * 3 = 12 ints   = 3 x int4     (48*g)
//   reward: 12 floats               = 3 x float4   (48*g)
//   mask  : 4 floats                = 1 x float4   (16*g)
// 28 x 1KB-per-wave loads in flight, no barriers, occupancy VGPR-limited only.
__global__ __launch_bounds__(BLOCK, 4) void shortloss_main(
    const float* __restrict__ out0,
    const float* __restrict__ out1,
    const float* __restrict__ out2,
    const int*   __restrict__ labels,   // [N,3] int32
    const float* __restrict__ mask,     // [N]
    const float* __restrict__ reward,   // [N,3]
    float4*      __restrict__ partials) // [NBLOCKS]
{
    const int tid = threadIdx.x;
    const long long g = (long long)blockIdx.x * BLOCK + tid;   // quad-row index

    const float* outs[3] = {out0, out1, out2};

    // ---- gather side data for my 4 rows ----
    float4 mkv = ((const float4*)mask)[g];
    const float mk[4] = {mkv.x, mkv.y, mkv.z, mkv.w};

    int lb[12];
    {
        const int4* lp = (const int4*)labels;
        #pragma unroll
        for (int j = 0; j < 3; ++j) {
            int4 t = lp[3 * g + j];
            lb[4*j+0] = t.x; lb[4*j+1] = t.y; lb[4*j+2] = t.z; lb[4*j+3] = t.w;
        }
    }
    float rw[12];
    {
        const float4* rp = (const float4*)reward;
        #pragma unroll
        for (int j = 0; j < 3; ++j) {
            float4 t = rp[3 * g + j];
            rw[4*j+0] = t.x; rw[4*j+1] = t.y; rw[4*j+2] = t.z; rw[4*j+3] = t.w;
        }
    }

    // ---- per-head: 7 x dwordx4 burst, then register-local row math ----
    float lsum[4] = {0.f, 0.f, 0.f, 0.f};
    int   ok[4]   = {1, 1, 1, 1};
    #pragma unroll
    for (int h = 0; h < 3; ++h) {
        float o[28];
        const float4* op = (const float4*)outs[h];
        #pragma unroll
        for (int j = 0; j < 7; ++j) {
            float4 t = op[7 * g + j];
            o[4*j+0] = t.x; o[4*j+1] = t.y; o[4*j+2] = t.z; o[4*j+3] = t.w;
        }
        #pragma unroll
        for (int i = 0; i < 4; ++i) {
            const int lbl = lb[3*i + h];
            const float* v = o + 7*i;

            // argmax, strict > (first-max tie-break, matches jnp.argmax)
            float best = v[0]; int bestc = 0;
            #pragma unroll
            for (int cc = 1; cc < 7; ++cc)
                if (v[cc] > best) { best = v[cc]; bestc = cc; }

            // gather true-class prob via select chain (no dynamic reg index)
            float opv = v[0];
            #pragma unroll
            for (int cc = 1; cc < 7; ++cc)
                opv = (lbl == cc) ? v[cc] : opv;

            lsum[i] += __logf(opv) * rw[3*i + h];
            ok[i]   &= (bestc == lbl) ? 1 : 0;
        }
    }

    float L = 0.0f;
    int   C = 0, V = 0;
    #pragma unroll
    for (int i = 0; i < 4; ++i) {
        const bool valid = mk[i] < 0.5f;
        V += valid ? 1 : 0;
        L += valid ? lsum[i] : 0.0f;
        C += (valid && ok[i]) ? 1 : 0;
    }

    // ---- block reduction (unchanged, proven) ----
    #pragma unroll
    for (int off = 32; off > 0; off >>= 1) {
        L += __shfl_down(L, off, 64);
        C += __shfl_down(C, off, 64);
        V += __shfl_down(V, off, 64);
    }
    __shared__ float sL[BLOCK / 64];
    __shared__ int   sC[BLOCK / 64], sV[BLOCK / 64];
    const int wave = tid >> 6;
    if ((tid & 63) == 0) { sL[wave] = L; sC[wave] = C; sV[wave] = V; }
    __syncthreads();
    if (tid == 0) {
        float l = 0.0f; int cc = 0, vv = 0;
        #pragma unroll
        for (int w = 0; w < BLOCK / 64; ++w) { l += sL[w]; cc += sC[w]; vv += sV[w]; }
        partials[blockIdx.x] = make_float4(l, (float)cc, (float)vv, 0.0f);
    }
}

__global__ __launch_bounds__(256) void shortloss_reduce(
    const float4* __restrict__ partials,
    float* __restrict__ out)
{
    float L = 0.0f, C = 0.0f, V = 0.0f;
    for (int i = threadIdx.x; i < NBLOCKS; i += 256) {
        float4 p = partials[i];
        L += p.x; C += p.y; V += p.z;
    }
    #pragma unroll
    for (int off = 32; off > 0; off >>= 1) {
        L += __shfl_down(L, off, 64);
        C += __shfl_down(C, off, 64);
        V += __shfl_down(V, off, 64);
    }
    __shared__ float sL[4], sC[4], sV[4];
    const int wave = threadIdx.x >> 6;
    if ((threadIdx.x & 63) == 0) { sL[wave] = L; sC[wave] = C; sV[wave] = V; }
    __syncthreads();
    if (threadIdx.x == 0) {
        float l = 0.0f, c = 0.0f, v = 0.0f;
        #pragma unroll
        for (int w = 0; w < 4; ++w) { l += sL[w]; c += sC[w]; v += sV[w]; }
        out[0] = -l / v;
        out[1] = c;
        out[2] = v;
    }
}

extern "C" void kernel_launch(void* const* d_in, const int* in_sizes, int n_in,
                              void* d_out, int out_size, void* d_ws, size_t ws_size,
                              hipStream_t stream) {
    const float* out0   = (const float*)d_in[0];
    const float* out1   = (const float*)d_in[1];
    const float* out2   = (const float*)d_in[2];
    const int*   labels = (const int*)  d_in[3];
    const float* mask   = (const float*)d_in[4];
    const float* reward = (const float*)d_in[5];

    float4* partials = (float4*)d_ws;   // 2048 * 16 B = 32 KB

    shortloss_main<<<NBLOCKS, BLOCK, 0, stream>>>(
        out0, out1, out2, labels, mask, reward, partials);
    shortloss_reduce<<<1, 256, 0, stream>>>(partials, (float*)d_out);
}